// Round 13
// baseline (285.922 us; speedup 1.0000x reference)
//
#include <hip/hip_runtime.h>
#include <math.h>

// Problem constants
#define B_   4
#define N_   4096
#define K_   32
#define C_   192
#define CH_  195          // C + 3 (logical GEMM K)
#define KPAD 224          // 7 x 32 ; rows: 0..2=dp, 3..7=0, 8..199=channels, 200..223=0
#define PTS  2            // points per group
#define NKT  7            // K-tiles
#define NNT  4            // N-tiles (64 cols / 16)
#define G_   8            // groups per block -> 16 consecutive points (one 64 B out-line)
#define SEG  (G_ * PTS)   // 16
#define GRID 1024         // exact-fit co-residency: 4 blocks/CU x 256 CU

using half8  = __attribute__((ext_vector_type(8))) _Float16;
using half2v = __attribute__((ext_vector_type(2))) _Float16;
using f32x4  = __attribute__((ext_vector_type(4))) float;

// Module-static device scratch (NOT d_ws — R4 post-mortem: overran ws_size).
__device__ _Float16 g_Wp[C_ * KPAD];                    // 86016 B (rows pre-scaled by BN inv)
__device__ _Float16 g_xT[(size_t)B_ * N_ * C_];         // 6291456 B
// Grid-barrier state: self-restoring (g_cnt returns to 0 each call; g_gen monotone).
__device__ int g_cnt = 0;
__device__ int g_gen = 0;

// Device-scope sense-reversing grid barrier. Safe because grid == exact
// co-residency capacity (all 1024 blocks resident before any spins).
__device__ __forceinline__ void grid_barrier(int tid) {
    __syncthreads();
    if (tid == 0) {
        const int mygen = __hip_atomic_load(&g_gen, __ATOMIC_ACQUIRE, __HIP_MEMORY_SCOPE_AGENT);
        __threadfence();   // device-scope release of g_xT / g_Wp writes (cross-XCD writeback)
        const int arrived = __hip_atomic_fetch_add(&g_cnt, 1, __ATOMIC_ACQ_REL, __HIP_MEMORY_SCOPE_AGENT);
        if (arrived == GRID - 1) {
            __hip_atomic_store(&g_cnt, 0, __ATOMIC_RELAXED, __HIP_MEMORY_SCOPE_AGENT);
            __hip_atomic_fetch_add(&g_gen, 1, __ATOMIC_RELEASE, __HIP_MEMORY_SCOPE_AGENT);
        } else {
            while (__hip_atomic_load(&g_gen, __ATOMIC_ACQUIRE, __HIP_MEMORY_SCOPE_AGENT) == mygen) {
                __builtin_amdgcn_s_sleep(2);
            }
        }
        __threadfence();   // acquire side
    }
    __syncthreads();
}

// 16-lane max reduction on the VALU via DPP (no DS pipe)
__device__ __forceinline__ float dpp_max16(float v) {
    int s;
    s = __builtin_amdgcn_update_dpp(0, __float_as_int(v), 0xB1,  0xF, 0xF, true); // quad xor1
    v = fmaxf(v, __int_as_float(s));
    s = __builtin_amdgcn_update_dpp(0, __float_as_int(v), 0x4E,  0xF, 0xF, true); // quad xor2
    v = fmaxf(v, __int_as_float(s));
    s = __builtin_amdgcn_update_dpp(0, __float_as_int(v), 0x141, 0xF, 0xF, true); // half-mirror
    v = fmaxf(v, __int_as_float(s));
    s = __builtin_amdgcn_update_dpp(0, __float_as_int(v), 0x140, 0xF, 0xF, true); // row mirror
    v = fmaxf(v, __int_as_float(s));
    return v;
}

// ---- single fused kernel: prep (transpose + W) -> grid barrier -> main ----
__global__ __launch_bounds__(256, 4) void la_all(
    const float* __restrict__ p,      // [B,N,3]
    const float* __restrict__ x,      // [B,C,N]
    const int*   __restrict__ idx,    // [B,N,K]
    const float* __restrict__ W,      // [C, C+3]
    const float* __restrict__ gamma_,
    const float* __restrict__ beta_,
    const float* __restrict__ rmean,
    const float* __restrict__ rvar,
    float* __restrict__ out)          // [B,C,N]
{
    __shared__ _Float16 hb[NKT * NNT * 64 * 8];   // 28672 B; phase-1 scratch unioned here
    __shared__ _Float16 s_o[C_][SEG];             // 6144 B: [channel][n-offset] fp16
    __shared__ float s_bias[C_], s_fr[32];

    const int tid  = threadIdx.x;
    const int lane = tid & 63;
    const int w    = tid >> 6;
    const int l15  = lane & 15;
    const int quad = lane >> 4;

    // ================= PHASE 1: x transpose tile + W convert =================
    {
        float (*s)[100] = reinterpret_cast<float(*)[100]>(hb);   // 12.8 KB scratch in hb
        const int bi = blockIdx.x;            // 0..1023, one 32n x 96c tile each
        const int tb = bi >> 8;
        const int c0 = ((bi >> 7) & 1) * 96;
        const int n0 = (bi & 127) * 32;
#pragma unroll
        for (int it = 0; it < 3; ++it) {
            const int c  = it * 32 + (tid >> 3);
            const int n4 = (tid & 7) * 4;
            const float4 v = *(const float4*)(x + ((size_t)tb * C_ + c0 + c) * N_ + n0 + n4);
            s[n4 + 0][c] = v.x; s[n4 + 1][c] = v.y; s[n4 + 2][c] = v.z; s[n4 + 3][c] = v.w;
        }
        __syncthreads();
#pragma unroll
        for (int it = 0; it < 2; ++it) {
            const int t = it * 256 + tid;
            if (t < 32 * 12) {
                const int n  = t / 12;
                const int ch = t - n * 12;
                const float4 f0 = *(const float4*)(&s[n][ch * 8 + 0]);
                const float4 f1 = *(const float4*)(&s[n][ch * 8 + 4]);
                half8 v;
                v[0] = (_Float16)f0.x; v[1] = (_Float16)f0.y;
                v[2] = (_Float16)f0.z; v[3] = (_Float16)f0.w;
                v[4] = (_Float16)f1.x; v[5] = (_Float16)f1.y;
                v[6] = (_Float16)f1.z; v[7] = (_Float16)f1.w;
                *(half8*)(g_xT + ((size_t)tb * N_ + n0 + n) * C_ + c0 + ch * 8) = v;
            }
        }
        // W -> fp16 [192][224], remapped K rows, BN scale folded (42 elems/block)
        if (tid < 42) {
            const int i = bi * 42 + tid;               // 1024*42 = 43008 = C_*KPAD
            const int o = i / KPAD, r = i - o * KPAD;
            const float inv = gamma_[o] * rsqrtf(rvar[o] + 1e-5f);
            float v = 0.0f;
            if (r < 3)                  v = W[o * CH_ + r];
            else if (r >= 8 && r < 200) v = W[o * CH_ + 3 + (r - 8)];
            g_Wp[i] = (_Float16)(v * inv);
        }
        // block-local init while waiting
        if (tid < C_) {
            const float inv = gamma_[tid] * rsqrtf(rvar[tid] + 1e-5f);
            s_bias[tid] = beta_[tid] - rmean[tid] * inv;
        }
        if (tid < 32) s_fr[tid] = 7.9577471546f * exp2f(-(float)tid * 0.2801808715263400f);
    }

    grid_barrier(tid);   // all g_xT / g_Wp visible device-wide

    // ================= PHASE 2: fused gather/embed/GEMM/max =================
    float sfr[8];
#pragma unroll
    for (int jj = 0; jj < 8; ++jj) sfr[jj] = s_fr[quad * 8 + jj];

    // XCD swizzle: consecutive same-XCD blocks -> consecutive 16-point segments
    const int q    = blockIdx.x & 7;
    const int sI   = blockIdx.x >> 3;          // 0..127
    const int seg  = q * (GRID / 8) + sI;
    const int bnS  = seg * SEG;
    const int b    = bnS >> 12;
    const int n0S  = bnS & (N_ - 1);

    const int colB = w * 16 + l15;    // phase-B column (n-tile = w)
    const int ptB  = colB >> 5;
    const int kB   = colB & 31;

    for (int g = 0; g < G_; ++g) {
        const int bn0 = bnS + g * PTS;

        // ---- Phase B: gather + PosPool embed -> hb (conflict-free frag order) ----
        {
            const int gp = bn0 + ptB;
            const int j  = idx[(size_t)gp * K_ + kB];
            const float* pj = p + (size_t)(b * N_ + j) * 3;
            const float* pn = p + (size_t)gp * 3;
            const float d0 = pj[0] - pn[0];
            const float d1 = pj[1] - pn[1];
            const float d2 = pj[2] - pn[2];
            const _Float16* xh = g_xT + ((size_t)b * N_ + j) * C_;

#pragma unroll
            for (int i6 = 0; i6 < 6; ++i6) {
                const int chunk = quad + 4 * i6;           // 0..23
                const half8 v = *(const half8*)(xh + chunk * 8);
                const float dd  = (chunk < 8) ? d0 : ((chunk < 16) ? d1 : d2);
                const float off = (chunk & 4) ? 0.25f : 0.0f;   // cos = sin(+1/4 rev)
                half8 hv;
#pragma unroll
                for (int jj = 0; jj < 8; jj += 2) {
                    const float pe0 = __builtin_amdgcn_sinf(fmaf(dd, sfr[jj],     off));
                    const float pe1 = __builtin_amdgcn_sinf(fmaf(dd, sfr[jj + 1], off));
                    const half2v pe2 = __builtin_bit_cast(half2v, __builtin_amdgcn_cvt_pkrtz(pe0, pe1));
                    half2v v2; v2[0] = v[jj]; v2[1] = v[jj + 1];
                    const half2v r2 = pe2 * v2 + pe2;   // v_pk_fma_f16: pe*(x+1)
                    hv[jj] = r2[0]; hv[jj + 1] = r2[1];
                }
                const int ro = chunk + 1;               // channel octets 1..24
                const int kt = ro >> 2, kq = ro & 3;
                *(half8*)(&hb[(size_t)((kt * NNT + w) * 64 + kq * 16 + l15) * 8]) = hv;
            }
            if (quad == 0) {        // octet 0: dp rows 0..2 + zeros
                half8 hv0 = (half8)(_Float16)0.0f;
                hv0[0] = (_Float16)d0; hv0[1] = (_Float16)d1; hv0[2] = (_Float16)d2;
                *(half8*)(&hb[(size_t)((0 * NNT + w) * 64 + 0 * 16 + l15) * 8]) = hv0;
            } else {                // octets 25..27: zero rows 200..223
                const int ro = 24 + quad;
                const int kt = ro >> 2, kq = ro & 3;
                *(half8*)(&hb[(size_t)((kt * NNT + w) * 64 + kq * 16 + l15) * 8]) = (half8)(_Float16)0.0f;
            }
        }
        __syncthreads();   // hb ready

        // ---- Phase C: MFMA GEMM  y[192 x 64] = Wp[192 x 224] * h[224 x 64] ----
        f32x4 acc[3][4];
#pragma unroll
        for (int i = 0; i < 3; ++i)
#pragma unroll
            for (int t = 0; t < 4; ++t) acc[i][t] = (f32x4)0.0f;

#pragma unroll
        for (int kt = 0; kt < NKT; ++kt) {
            const int k0 = kt * 32 + quad * 8;
            half8 a[3], bf[4];
#pragma unroll
            for (int i = 0; i < 3; ++i) {
                const int m = (w * 3 + i) * 16 + l15;
                a[i] = *(const half8*)(g_Wp + (size_t)m * KPAD + k0);   // L1/L2-hot
            }
#pragma unroll
            for (int t = 0; t < 4; ++t)
                bf[t] = *(const half8*)(&hb[(size_t)((kt * NNT + t) * 64 + lane) * 8]);
#pragma unroll
            for (int i = 0; i < 3; ++i)
#pragma unroll
                for (int t = 0; t < 4; ++t)
                    acc[i][t] = __builtin_amdgcn_mfma_f32_16x16x32_f16(a[i], bf[t], acc[i][t], 0, 0, 0);
        }

        // ---- Epilogue: max over 32 neighbors (DPP) -> +bias -> ReLU -> s_o fp16 ----
        // C/D layout: col = lane&15, row = quad*4 + reg
#pragma unroll
        for (int i = 0; i < 3; ++i) {
            const int mbase = (w * 3 + i) * 16 + quad * 4;
#pragma unroll
            for (int pt = 0; pt < PTS; ++pt) {
                const f32x4 va = acc[i][2 * pt];
                const f32x4 vb = acc[i][2 * pt + 1];
#pragma unroll
                for (int r = 0; r < 4; ++r) {
                    float v = fmaxf(va[r], vb[r]);
                    v = dpp_max16(v);
                    if (l15 == 0) {
                        const int m = mbase + r;
                        s_o[m][g * PTS + pt] = (_Float16)fmaxf(v + s_bias[m], 0.0f);
                    }
                }
            }
        }
        __syncthreads();   // hb reads done (safe to overwrite) + s_o slice committed
    }

    // ---- one full 64 B line per channel row, written exactly once ----
    if (tid < C_) {
        float* op = out + ((size_t)b * C_ + tid) * N_ + n0S;
#pragma unroll
        for (int k4 = 0; k4 < 4; ++k4) {
            float4 o4;
            o4.x = (float)s_o[tid][k4 * 4 + 0];
            o4.y = (float)s_o[tid][k4 * 4 + 1];
            o4.z = (float)s_o[tid][k4 * 4 + 2];
            o4.w = (float)s_o[tid][k4 * 4 + 3];
            *(float4*)(op + k4 * 4) = o4;
        }
    }
}

extern "C" void kernel_launch(void* const* d_in, const int* in_sizes, int n_in,
                              void* d_out, int out_size, void* d_ws, size_t ws_size,
                              hipStream_t stream) {
    (void)in_sizes; (void)n_in; (void)out_size; (void)d_ws; (void)ws_size;
    const float* p      = (const float*)d_in[0];
    const float* x      = (const float*)d_in[1];
    const int*   idx    = (const int*)d_in[2];
    const float* W      = (const float*)d_in[3];
    const float* gamma_ = (const float*)d_in[4];
    const float* beta_  = (const float*)d_in[5];
    const float* rmean  = (const float*)d_in[6];
    const float* rvar   = (const float*)d_in[7];
    float* out = (float*)d_out;

    la_all<<<GRID, 256, 0, stream>>>(p, x, idx, W, gamma_, beta_, rmean, rvar, out);
}

// Round 14
// 169.956 us; speedup vs baseline: 1.6823x; 1.6823x over previous
//
#include <hip/hip_runtime.h>
#include <math.h>

// Problem constants
#define B_   4
#define N_   4096
#define K_   32
#define C_   192
#define CH_  195          // C + 3 (logical GEMM K)
#define KPAD 224          // 7 x 32 ; rows: 0..2=dp, 3..7=0, 8..199=channels, 200..223=0
#define PTS  2            // points per block
#define NKT  7            // K-tiles
#define NNT  4            // N-tiles (64 cols / 16)
#define GRID ((B_ * N_) / PTS)   // 8192 blocks, dense dispatch (stagger + L2 write coalescing)

using half8  = __attribute__((ext_vector_type(8))) _Float16;
using half2v = __attribute__((ext_vector_type(2))) _Float16;
using f32x4  = __attribute__((ext_vector_type(4))) float;

// Module-static device scratch (NOT d_ws — R4 post-mortem: overran ws_size).
__device__ _Float16 g_Wp[C_ * KPAD];                    // 86016 B (rows pre-scaled by BN inv)
__device__ _Float16 g_xT[(size_t)B_ * N_ * C_];         // 6291456 B

__device__ __forceinline__ half2v hmax2(half2v a, half2v b) {
#if __has_builtin(__builtin_elementwise_max)
    return __builtin_elementwise_max(a, b);
#else
    half2v r;
    r[0] = (a[0] > b[0]) ? a[0] : b[0];
    r[1] = (a[1] > b[1]) ? a[1] : b[1];
    return r;
#endif
}

// 16-lane packed-fp16 max reduction via DPP (two outputs per chain)
__device__ __forceinline__ half2v dpp_hmax16(half2v v) {
    int s;
    s = __builtin_amdgcn_update_dpp(0, __builtin_bit_cast(int, v), 0xB1,  0xF, 0xF, true); // quad xor1
    v = hmax2(v, __builtin_bit_cast(half2v, s));
    s = __builtin_amdgcn_update_dpp(0, __builtin_bit_cast(int, v), 0x4E,  0xF, 0xF, true); // quad xor2
    v = hmax2(v, __builtin_bit_cast(half2v, s));
    s = __builtin_amdgcn_update_dpp(0, __builtin_bit_cast(int, v), 0x141, 0xF, 0xF, true); // half-mirror
    v = hmax2(v, __builtin_bit_cast(half2v, s));
    s = __builtin_amdgcn_update_dpp(0, __builtin_bit_cast(int, v), 0x140, 0xF, 0xF, true); // row mirror
    v = hmax2(v, __builtin_bit_cast(half2v, s));
    return v;
}

// ---- fused prep: blocks 0..1023 transpose x -> g_xT ; blocks 1024.. convert W ----
__global__ __launch_bounds__(256) void prep(const float* __restrict__ x,
                                            const float* __restrict__ W,
                                            const float* __restrict__ gamma_,
                                            const float* __restrict__ rvar) {
    __shared__ float s[32][100];
    const int tid = threadIdx.x;
    if (blockIdx.x < 1024) {
        const int bi = blockIdx.x;
        const int b  = bi >> 8;
        const int c0 = ((bi >> 7) & 1) * 96;
        const int n0 = (bi & 127) * 32;
#pragma unroll
        for (int it = 0; it < 3; ++it) {
            const int c  = it * 32 + (tid >> 3);
            const int n4 = (tid & 7) * 4;
            const float4 v = *(const float4*)(x + ((size_t)b * C_ + c0 + c) * N_ + n0 + n4);
            s[n4 + 0][c] = v.x; s[n4 + 1][c] = v.y; s[n4 + 2][c] = v.z; s[n4 + 3][c] = v.w;
        }
        __syncthreads();
#pragma unroll
        for (int it = 0; it < 2; ++it) {
            const int t = it * 256 + tid;
            if (t < 32 * 12) {
                const int n  = t / 12;
                const int ch = t - n * 12;
                const float4 f0 = *(const float4*)(&s[n][ch * 8 + 0]);
                const float4 f1 = *(const float4*)(&s[n][ch * 8 + 4]);
                half8 v;
                v[0] = (_Float16)f0.x; v[1] = (_Float16)f0.y;
                v[2] = (_Float16)f0.z; v[3] = (_Float16)f0.w;
                v[4] = (_Float16)f1.x; v[5] = (_Float16)f1.y;
                v[6] = (_Float16)f1.z; v[7] = (_Float16)f1.w;
                *(half8*)(g_xT + ((size_t)b * N_ + n0 + n) * C_ + c0 + ch * 8) = v;
            }
        }
    } else {
        const int i = (blockIdx.x - 1024) * 256 + tid;
        if (i < C_ * KPAD) {
            const int o = i / KPAD, r = i - o * KPAD;
            const float inv = gamma_[o] * rsqrtf(rvar[o] + 1e-5f);  // BN scale folded into W
            float v = 0.0f;
            if (r < 3)                  v = W[o * CH_ + r];
            else if (r >= 8 && r < 200) v = W[o * CH_ + 3 + (r - 8)];
            g_Wp[i] = (_Float16)(v * inv);
        }
    }
}

// ---- main fused kernel: one block = 2 points, 256 threads, 1 barrier total ----
__global__ __launch_bounds__(256, 5) void la_mfma(
    const float* __restrict__ p,      // [B,N,3]
    const int*   __restrict__ idx,    // [B,N,K]
    const float* __restrict__ gamma_,
    const float* __restrict__ beta_,
    const float* __restrict__ rmean,
    const float* __restrict__ rvar,
    float* __restrict__ out)          // [B,C,N]
{
    __shared__ _Float16 hb[NKT * NNT * 64 * 8];   // 28672 B, B-fragment order
    __shared__ float s_bias[C_], s_fr[32];

    const int tid  = threadIdx.x;
    const int lane = tid & 63;
    const int w    = tid >> 6;
    const int l15  = lane & 15;
    const int quad = lane >> 4;

    // XCD swizzle: keep each XCD inside one batch's xT slice (L2-resident)
    const int q  = blockIdx.x & 7;
    const int sI = blockIdx.x >> 3;
    const int L  = q * (GRID / 8) + sI;
    const int bn0 = L * PTS;
    const int b   = bn0 >> 12;
    const int n0  = bn0 & (N_ - 1);

    if (tid < C_) {
        const float inv = gamma_[tid] * rsqrtf(rvar[tid] + 1e-5f);
        s_bias[tid] = beta_[tid] - rmean[tid] * inv;   // scale part lives in g_Wp
    }
    // s_fr[f] = (50 / 2pi) * 500^(-f/32)   (v_sin/v_cos take revolutions)
    if (tid < 32) s_fr[tid] = 7.9577471546f * exp2f(-(float)tid * 0.2801808715263400f);
    __syncthreads();

    // ---- Phase B: conflict-free frag-order build of h tile ----
    {
        const int col = w * 16 + l15;     // n-tile = w
        const int pt  = col >> 5;
        const int k   = col & 31;
        const int gp  = bn0 + pt;
        const int j   = idx[(size_t)gp * K_ + k];
        const float d0 = p[(size_t)(b * N_ + j) * 3 + 0] - p[(size_t)gp * 3 + 0];
        const float d1 = p[(size_t)(b * N_ + j) * 3 + 1] - p[(size_t)gp * 3 + 1];
        const float d2 = p[(size_t)(b * N_ + j) * 3 + 2] - p[(size_t)gp * 3 + 2];
        const _Float16* xh = g_xT + ((size_t)b * N_ + j) * C_;

        // per-thread frequency set: f = quad*8 + jj (invariant across chunks, proven)
        float sfr[8];
#pragma unroll
        for (int jj = 0; jj < 8; ++jj) sfr[jj] = s_fr[quad * 8 + jj];

        // chunk pairs (cS, cS+4) share d AND the full angle set: sin & cos of same angle
#pragma unroll
        for (int dp3 = 0; dp3 < 3; ++dp3) {
            const int cS = quad + 8 * dp3;          // sin chunk: 0..3 / 8..11 / 16..19
            const int cC = cS + 4;                  // cos partner
            const half8 vS = *(const half8*)(xh + cS * 8);
            const half8 vC = *(const half8*)(xh + cC * 8);
            const float dd = (dp3 == 0) ? d0 : ((dp3 == 1) ? d1 : d2);
            half8 hS, hC;
#pragma unroll
            for (int jj = 0; jj < 8; jj += 2) {
                const float a0 = dd * sfr[jj];
                const float a1 = dd * sfr[jj + 1];
                const half2v ps = __builtin_bit_cast(half2v, __builtin_amdgcn_cvt_pkrtz(
                    __builtin_amdgcn_sinf(a0), __builtin_amdgcn_sinf(a1)));
                const half2v pc = __builtin_bit_cast(half2v, __builtin_amdgcn_cvt_pkrtz(
                    __builtin_amdgcn_cosf(a0), __builtin_amdgcn_cosf(a1)));
                half2v vs2; vs2[0] = vS[jj]; vs2[1] = vS[jj + 1];
                half2v vc2; vc2[0] = vC[jj]; vc2[1] = vC[jj + 1];
                const half2v rs = ps * vs2 + ps;    // v_pk_fma_f16: pe*(x+1)
                const half2v rc = pc * vc2 + pc;
                hS[jj] = rs[0]; hS[jj + 1] = rs[1];
                hC[jj] = rc[0]; hC[jj + 1] = rc[1];
            }
            {
                const int ro = cS + 1, kt = ro >> 2, kq = ro & 3;
                *(half8*)(&hb[(size_t)((kt * NNT + w) * 64 + kq * 16 + l15) * 8]) = hS;
            }
            {
                const int ro = cC + 1, kt = ro >> 2, kq = ro & 3;
                *(half8*)(&hb[(size_t)((kt * NNT + w) * 64 + kq * 16 + l15) * 8]) = hC;
            }
        }
        if (quad == 0) {        // octet 0: dp rows 0..2 + zeros
            half8 hv0 = (half8)(_Float16)0.0f;
            hv0[0] = (_Float16)d0; hv0[1] = (_Float16)d1; hv0[2] = (_Float16)d2;
            *(half8*)(&hb[(size_t)((0 * NNT + w) * 64 + 0 * 16 + l15) * 8]) = hv0;
        } else {                // octets 25..27: zero rows 200..223
            const int ro = 24 + quad;
            const int kt = ro >> 2, kq = ro & 3;
            *(half8*)(&hb[(size_t)((kt * NNT + w) * 64 + kq * 16 + l15) * 8]) = (half8)(_Float16)0.0f;
        }
    }
    __syncthreads();   // the ONLY barrier

    // ---- Phase C: MFMA GEMM  y[192 x 64] = Wp[192 x 224] * h[224 x 64] ----
    f32x4 acc[3][4];
#pragma unroll
    for (int i = 0; i < 3; ++i)
#pragma unroll
        for (int t = 0; t < 4; ++t) acc[i][t] = (f32x4)0.0f;

#pragma unroll
    for (int kt = 0; kt < NKT; ++kt) {
        const int k0 = kt * 32 + quad * 8;
        half8 a[3], bf[4];
#pragma unroll
        for (int i = 0; i < 3; ++i) {
            const int m = (w * 3 + i) * 16 + l15;
            a[i] = *(const half8*)(g_Wp + (size_t)m * KPAD + k0);   // L1/L2-hot
        }
#pragma unroll
        for (int t = 0; t < 4; ++t)
            bf[t] = *(const half8*)(&hb[(size_t)((kt * NNT + t) * 64 + lane) * 8]);
#pragma unroll
        for (int i = 0; i < 3; ++i)
#pragma unroll
            for (int t = 0; t < 4; ++t)
                acc[i][t] = __builtin_amdgcn_mfma_f32_16x16x32_f16(a[i], bf[t], acc[i][t], 0, 0, 0);
    }

    // ---- Epilogue: packed-fp16 DPP max over 32 neighbors -> +bias -> ReLU ->
    //      direct 8 B store (no LDS funnel, no second barrier).
    // C/D layout: col = lane&15, row = quad*4 + reg ; acc[i][0..1]=pt0, [2..3]=pt1
    // cvt RTZ is monotone -> commutes exactly with max; pre-bias |err| <= ~0.008.
#pragma unroll
    for (int i = 0; i < 3; ++i) {
        const int mbase = (w * 3 + i) * 16 + quad * 4;
#pragma unroll
        for (int r = 0; r < 4; ++r) {
            const float y0 = fmaxf(acc[i][0][r], acc[i][1][r]);   // pt0 over 2 n-tiles
            const float y1 = fmaxf(acc[i][2][r], acc[i][3][r]);   // pt1 over 2 n-tiles
            half2v h = __builtin_bit_cast(half2v, __builtin_amdgcn_cvt_pkrtz(y0, y1));
            h = dpp_hmax16(h);                                    // max over 16 lanes (k)
            if (l15 == 0) {
                const int m = mbase + r;
                const float bia = s_bias[m];
                float2 o2;
                o2.x = fmaxf((float)h[0] + bia, 0.0f);
                o2.y = fmaxf((float)h[1] + bia, 0.0f);
                *(float2*)(out + ((size_t)b * C_ + m) * N_ + n0) = o2;
            }
        }
    }
}

extern "C" void kernel_launch(void* const* d_in, const int* in_sizes, int n_in,
                              void* d_out, int out_size, void* d_ws, size_t ws_size,
                              hipStream_t stream) {
    (void)in_sizes; (void)n_in; (void)out_size; (void)d_ws; (void)ws_size;
    const float* p      = (const float*)d_in[0];
    const float* x      = (const float*)d_in[1];
    const int*   idx    = (const int*)d_in[2];
    const float* W      = (const float*)d_in[3];
    const float* gamma_ = (const float*)d_in[4];
    const float* beta_  = (const float*)d_in[5];
    const float* rmean  = (const float*)d_in[6];
    const float* rvar   = (const float*)d_in[7];
    float* out = (float*)d_out;

    prep<<<1024 + (C_ * KPAD + 255) / 256, 256, 0, stream>>>(x, W, gamma_, rvar);
    la_mfma<<<GRID, 256, 0, stream>>>(p, idx, gamma_, beta_, rmean, rvar, out);
}